// Round 7
// baseline (182.690 us; speedup 1.0000x reference)
//
#include <hip/hip_runtime.h>
#include <hip/hip_fp16.h>

// Batched 5-point-stencil Jacobi: x <- invD*(b - M x), 20 sweeps.
// B=16, N=512. Structure = fixed stencil (right,left,down,up), SEG=511*512.
// R6: 4 dispatches total. Launch 1 fuses the coefficient fold (Mn=-invD*M,
// c=invD*b, computed per-block from raw inputs, kept in registers) with the
// first 5 fused sweeps, and writes tile Mn/c for launches 2-4. Tiles grown to
// 128x64 (512 threads, 5 groups/thread) -> region redundancy 1.41 -> 1.195.

#define GN   512
#define GNN  (GN * GN)          // 2^18
#define GB   16
#define SEG  (GN * (GN - 1))    // 261632
#define SEG4 (4 * SEG)

// tile geometry (5 fused sweeps, tile 128 cols x 64 rows)
#define TW2   128
#define TH2   64
#define NGC2  34                // col groups in region (cols rel -4..131)
#define NRR2  72                // region rows (rel -4..67)
#define NGRP2 (NGC2 * NRR2)     // 2448
#define XSTR  148               // x LDS row stride (halfs), cols rel -8..135 +pad
#define XROWS 74                // staged rows rel -5..68
#define XGC   36                // staged col groups

struct alignas(8)  h4  { __half h[4]; };
struct alignas(16) hx8 { __half h[8]; };

__device__ inline float h2f(__half v) { return __half2float(v); }

__device__ inline h4 f4h(float a, float b, float c, float d) {
    h4 r;
    *(__half2*)&r.h[0] = __floats2half2_rn(a, b);
    *(__half2*)&r.h[2] = __floats2half2_rn(c, d);
    return r;
}

// one 4-point group: o = c + m.(x neighbors), from LDS buffer s at base
__device__ inline void grp4(const __half* __restrict__ s, const int base,
                            const hx8& m01, const hx8& m23, const h4& cc,
                            float o[4])
{
    const h4 xc = *(const h4*)(s + base);
    const h4 xu = *(const h4*)(s + base - XSTR);
    const h4 xd = *(const h4*)(s + base + XSTR);
    const float xl = h2f(s[base - 1]);
    const float xr = h2f(s[base + 4]);
    const float x0 = h2f(xc.h[0]), x1 = h2f(xc.h[1]);
    const float x2 = h2f(xc.h[2]), x3 = h2f(xc.h[3]);

    float a;
    a = h2f(cc.h[0]);
    a = fmaf(h2f(m01.h[0]), x1, a);
    a = fmaf(h2f(m01.h[1]), xl, a);
    a = fmaf(h2f(m01.h[2]), h2f(xd.h[0]), a);
    a = fmaf(h2f(m01.h[3]), h2f(xu.h[0]), a);
    o[0] = a;
    a = h2f(cc.h[1]);
    a = fmaf(h2f(m01.h[4]), x2, a);
    a = fmaf(h2f(m01.h[5]), x0, a);
    a = fmaf(h2f(m01.h[6]), h2f(xd.h[1]), a);
    a = fmaf(h2f(m01.h[7]), h2f(xu.h[1]), a);
    o[1] = a;
    a = h2f(cc.h[2]);
    a = fmaf(h2f(m23.h[0]), x3, a);
    a = fmaf(h2f(m23.h[1]), x1, a);
    a = fmaf(h2f(m23.h[2]), h2f(xd.h[2]), a);
    a = fmaf(h2f(m23.h[3]), h2f(xu.h[2]), a);
    o[2] = a;
    a = h2f(cc.h[3]);
    a = fmaf(h2f(m23.h[4]), xr, a);
    a = fmaf(h2f(m23.h[5]), x2, a);
    a = fmaf(h2f(m23.h[6]), h2f(xd.h[3]), a);
    a = fmaf(h2f(m23.h[7]), h2f(xu.h[3]), a);
    o[3] = a;
}

// the 4 internal ping-pong phases (sweeps 1..4 of a 5-sweep launch)
__device__ inline void phases4(__half* __restrict__ xsA, __half* __restrict__ xsB,
                               const hx8 (&m01)[5], const hx8 (&m23)[5],
                               const h4 (&cc)[5], const int (&lb)[5],
                               const bool (&act)[5])
{
#pragma unroll
    for (int k = 0; k < 5; ++k) {
        if (!act[k]) continue;
        float o[4];
        grp4(xsA, lb[k], m01[k], m23[k], cc[k], o);
        *(h4*)(xsB + lb[k]) = f4h(o[0], o[1], o[2], o[3]);
    }
    __syncthreads();
#pragma unroll
    for (int k = 0; k < 5; ++k) {
        if (!act[k]) continue;
        float o[4];
        grp4(xsB, lb[k], m01[k], m23[k], cc[k], o);
        *(h4*)(xsA + lb[k]) = f4h(o[0], o[1], o[2], o[3]);
    }
    __syncthreads();
#pragma unroll
    for (int k = 0; k < 5; ++k) {
        if (!act[k]) continue;
        float o[4];
        grp4(xsA, lb[k], m01[k], m23[k], cc[k], o);
        *(h4*)(xsB + lb[k]) = f4h(o[0], o[1], o[2], o[3]);
    }
    __syncthreads();
#pragma unroll
    for (int k = 0; k < 5; ++k) {
        if (!act[k]) continue;
        float o[4];
        grp4(xsB, lb[k], m01[k], m23[k], cc[k], o);
        *(h4*)(xsA + lb[k]) = f4h(o[0], o[1], o[2], o[3]);
    }
    __syncthreads();
}

// ---- Launch 1: fold fused with sweeps 1-5. Coeffs computed from raw fp32
// inputs per region group (registers), tile coeffs written to ws for L2-4.
__global__ __launch_bounds__(512, 4) void fsweep5(
    const float* __restrict__ u,
    const float* __restrict__ bvec,
    const float* __restrict__ Mv,
    const float* __restrict__ invD,
    __half* __restrict__ MnW,    // [B][NN][4] out
    __half* __restrict__ cW,     // [B][NN] out
    __half* __restrict__ xout)   // [B][NN] out (after 5 sweeps)
{
    __shared__ __half xsA[XROWS * XSTR];
    __shared__ __half xsB[XROWS * XSTR];

    const int tid  = threadIdx.x;
    const int tile = blockIdx.x;          // 512 blocks
    const int bi   = tile >> 5;
    const int tl   = tile & 31;           // 4x8 tiles per image
    const int j0   = (tl & 3) << 7;
    const int i0   = (tl >> 2) << 6;

    const float* __restrict__ ub  = u    + ((size_t)bi << 18);
    const float* __restrict__ mvb = Mv   + (size_t)bi * SEG4;

    // stage x = fp32 u region (rows rel -5..68, cols rel -8..135); 0 outside
    for (int v = tid; v < XROWS * XGC; v += 512) {
        const int r = v / XGC;
        const int g = v - r * XGC;
        const int gi = i0 + r - 5;
        const int gj = j0 - 8 + (g << 2);
        h4 val{};
        if ((unsigned)gi < GN && (unsigned)gj <= GN - 4) {
            const float4 f = *(const float4*)(ub + ((size_t)gi << 9) + gj);
            val = f4h(f.x, f.y, f.z, f.w);
        }
        *(h4*)(xsA + r * XSTR + (g << 2)) = val;
    }

    // per-thread coeffs for 5 fixed region groups, computed from raw inputs
    hx8 m01[5], m23[5]; h4 cc[5];
    int lb[5]; int rrA[5], gcA[5]; bool act[5];
#pragma unroll
    for (int k = 0; k < 5; ++k) {
        int gidx = tid + (k << 9);
        act[k] = gidx < NGRP2;
        if (gidx >= NGRP2) gidx = NGRP2 - 1;
        const int r   = gidx / NGC2;
        const int g   = gidx - r * NGC2;
        const int rr  = r - 4;                  // row rel -4..67
        const int gcc = (g << 2) - 4;           // col rel -4..128 (mult of 4)
        rrA[k] = rr; gcA[k] = gcc;
        lb[k] = (rr + 5) * XSTR + gcc + 8;
        const int gi = i0 + rr;
        const int gj = j0 + gcc;
        hx8 w01{}, w23{}; h4 ch{};
        if ((unsigned)gi < GN && (unsigned)gj <= GN - 4) {
            const size_t pg = ((size_t)bi << 18) + ((size_t)gi << 9) + gj;
            const float4 dd  = *(const float4*)(invD + pg);
            const float4 bb4 = *(const float4*)(bvec + pg);
            float4 md4 = make_float4(0.f, 0.f, 0.f, 0.f);
            float4 mu4 = make_float4(0.f, 0.f, 0.f, 0.f);
            if (gi < GN - 1) md4 = *(const float4*)(mvb + 2 * SEG + ((size_t)gi << 9) + gj);
            if (gi > 0)      mu4 = *(const float4*)(mvb + 3 * SEG + (((size_t)gi - 1) << 9) + gj);
            const float dv[4]  = {dd.x, dd.y, dd.z, dd.w};
            const float bv[4]  = {bb4.x, bb4.y, bb4.z, bb4.w};
            const float mdv[4] = {md4.x, md4.y, md4.z, md4.w};
            const float muv[4] = {mu4.x, mu4.y, mu4.z, mu4.w};
            const int e0 = gi * (GN - 1) + gj;
#pragma unroll
            for (int e = 0; e < 4; ++e) {
                const int j = gj + e;
                const float mr = (j < GN - 1) ? mvb[e0 + e]           : 0.0f;
                const float ml = (j > 0)      ? mvb[SEG + e0 + e - 1] : 0.0f;
                const __half2 a  = __floats2half2_rn(-dv[e] * mr, -dv[e] * ml);
                const __half2 b2 = __floats2half2_rn(-dv[e] * mdv[e], -dv[e] * muv[e]);
                if (e < 2) { *(__half2*)&w01.h[4*e]       = a; *(__half2*)&w01.h[4*e+2]       = b2; }
                else       { *(__half2*)&w23.h[4*(e-2)]   = a; *(__half2*)&w23.h[4*(e-2)+2]   = b2; }
                ch.h[e] = __float2half_rn(dv[e] * bv[e]);
            }
            // write tile coeffs for launches 2-4 (each tile point exactly once)
            if ((unsigned)rr < TH2 && (unsigned)gcc < TW2) {
                *(hx8*)(MnW + (pg << 2))     = w01;
                *(hx8*)(MnW + (pg << 2) + 8) = w23;
                *(h4*)(cW + pg) = ch;
            }
        }
        m01[k] = w01; m23[k] = w23; cc[k] = ch;
    }
    __syncthreads();

    phases4(xsA, xsB, m01, m23, cc, lb, act);   // sweeps 1-4

    // sweep 5: A -> global (tile only), fp16
#pragma unroll
    for (int k = 0; k < 5; ++k) {
        if (!act[k]) continue;
        if ((unsigned)rrA[k] >= TH2 || (unsigned)gcA[k] >= TW2) continue;
        float o[4];
        grp4(xsA, lb[k], m01[k], m23[k], cc[k], o);
        const size_t p = ((size_t)bi << 18) + (size_t)(i0 + rrA[k]) * GN + j0 + gcA[k];
        *(h4*)(xout + p) = f4h(o[0], o[1], o[2], o[3]);
    }
}

// ---- Launches 2-4: 5 fused sweeps from ws (fp16 Mn/c/x). Out-of-region
// coeff reads wrap within ws (finite fp16 garbage only; image-boundary edges
// have folded-zero coefficients so fringe values never reach the tile).
template<bool FINAL>
__global__ __launch_bounds__(512, 4) void sweep5w(
    const __half* __restrict__ x,
    const __half* __restrict__ cvec,
    const __half* __restrict__ Mn,
    void* __restrict__ xout)
{
    __shared__ __half xsA[XROWS * XSTR];
    __shared__ __half xsB[XROWS * XSTR];

    const int tid  = threadIdx.x;
    const int tile = blockIdx.x;          // 512 blocks
    const int bi   = tile >> 5;
    const int tl   = tile & 31;
    const int j0   = (tl & 3) << 7;
    const int i0   = (tl >> 2) << 6;

    const __half* __restrict__ xb = x + ((size_t)bi << 18);

    // stage x region; 0 outside image
    for (int v = tid; v < XROWS * XGC; v += 512) {
        const int r = v / XGC;
        const int g = v - r * XGC;
        const int gi = i0 + r - 5;
        const int gj = j0 - 8 + (g << 2);
        h4 val{};
        if ((unsigned)gi < GN && (unsigned)gj <= GN - 4)
            val = *(const h4*)(xb + ((size_t)gi << 9) + gj);
        *(h4*)(xsA + r * XSTR + (g << 2)) = val;
    }

    hx8 m01[5], m23[5]; h4 cc[5];
    int lb[5]; int rrA[5], gcA[5]; bool act[5];
#pragma unroll
    for (int k = 0; k < 5; ++k) {
        int gidx = tid + (k << 9);
        act[k] = gidx < NGRP2;
        if (gidx >= NGRP2) gidx = NGRP2 - 1;
        const int r   = gidx / NGC2;
        const int g   = gidx - r * NGC2;
        const int rr  = r - 4;
        const int gcc = (g << 2) - 4;
        rrA[k] = rr; gcA[k] = gcc;
        lb[k] = (rr + 5) * XSTR + gcc + 8;
        const long pg = ((long)bi << 18) + (long)(i0 + rr) * GN + (j0 + gcc);
        const hx8* mp = (const hx8*)(Mn + (pg << 2));    // pg%4==0 -> 16B ok
        m01[k] = mp[0];
        m23[k] = mp[1];
        cc[k]  = *(const h4*)(cvec + pg);
    }
    __syncthreads();

    phases4(xsA, xsB, m01, m23, cc, lb, act);   // 4 sweeps

    // final sweep: A -> global (tile only)
#pragma unroll
    for (int k = 0; k < 5; ++k) {
        if (!act[k]) continue;
        if ((unsigned)rrA[k] >= TH2 || (unsigned)gcA[k] >= TW2) continue;
        float o[4];
        grp4(xsA, lb[k], m01[k], m23[k], cc[k], o);
        const size_t p = ((size_t)bi << 18) + (size_t)(i0 + rrA[k]) * GN + j0 + gcA[k];
        if (FINAL)
            *(float4*)((float*)xout + p) = make_float4(o[0], o[1], o[2], o[3]);
        else
            *(h4*)((__half*)xout + p) = f4h(o[0], o[1], o[2], o[3]);
    }
}

// ---- fp32 fallback (ws too small): x' = invD*(b - M x), 4 pts/thread ----
__global__ __launch_bounds__(256) void jac4_plain(
    const float* __restrict__ x,
    const float* __restrict__ bvec,
    const float* __restrict__ Mv,
    const float* __restrict__ invD,
    float* __restrict__ xout)
{
    const int t  = blockIdx.x * 256 + threadIdx.x;
    const int q  = t << 2;
    const int bi = q >> 18;
    const int p  = q & (GNN - 1);
    const int i  = p >> 9;
    const int j  = p & (GN - 1);

    const float* __restrict__ xb = x  + ((size_t)bi << 18);
    const float* __restrict__ mb = Mv + (size_t)bi * SEG4;

    const float4 xc = *(const float4*)(xb + p);
    const float  xl = (j > 0)      ? xb[p - 1] : 0.0f;
    const float  xr = (j < GN - 4) ? xb[p + 4] : 0.0f;
    float4 xu = make_float4(0.f, 0.f, 0.f, 0.f);
    float4 xd = make_float4(0.f, 0.f, 0.f, 0.f);
    float4 m2 = make_float4(0.f, 0.f, 0.f, 0.f);
    float4 m3 = make_float4(0.f, 0.f, 0.f, 0.f);
    if (i < GN - 1) { xd = *(const float4*)(xb + p + GN); m2 = *(const float4*)(mb + 2 * SEG + p); }
    if (i > 0)      { xu = *(const float4*)(xb + p - GN); m3 = *(const float4*)(mb + 3 * SEG + p - GN); }
    const float* __restrict__ m0 = mb + i * (GN - 1) + j;
    const float* __restrict__ m1 = mb + SEG + i * (GN - 1) + j - 1;
    const float m00 = m0[0], m01 = m0[1], m02 = m0[2], m03 = m0[3];
    const float m10 = m1[0], m11 = m1[1], m12 = m1[2], m13 = m1[3];

    const float4 bb = *(const float4*)(bvec + (size_t)q);
    const float4 dd = *(const float4*)(invD + (size_t)q);

    float4 o;
    o.x = dd.x * (bb.x - (m00 * xc.y + m10 * xl   + m2.x * xd.x + m3.x * xu.x));
    o.y = dd.y * (bb.y - (m01 * xc.z + m11 * xc.x + m2.y * xd.y + m3.y * xu.y));
    o.z = dd.z * (bb.z - (m02 * xc.w + m12 * xc.y + m2.z * xd.z + m3.z * xu.z));
    o.w = dd.w * (bb.w - (m03 * xr   + m13 * xc.z + m2.w * xd.w + m3.w * xu.w));

    *(float4*)(xout + (size_t)q) = o;
}

extern "C" void kernel_launch(void* const* d_in, const int* in_sizes, int n_in,
                              void* d_out, int out_size, void* d_ws, size_t ws_size,
                              hipStream_t stream)
{
    const float* u    = (const float*)d_in[0];
    const float* bvec = (const float*)d_in[1];
    const float* Mv   = (const float*)d_in[2];
    const float* invD = (const float*)d_in[3];
    const int maxiter = 20;                      // fixed by setup_inputs

    float* out = (float*)d_out;
    const size_t nPts  = (size_t)GB * GNN;       // 4,194,304
    // layout: xa, xb, Mn, c, tail pad (wrapped coeff reads stay in-bounds)
    const size_t needB = (7 * nPts + 32768) * sizeof(__half);

    if (ws_size >= needB) {
        __half* xa = (__half*)d_ws;
        __half* xb = xa + nPts;
        __half* Mn = xb + nPts;
        __half* c  = Mn + 4 * nPts;

        const dim3 blk(512);
        const dim3 grd(512);
        // sweeps 1-5 (+ fold), 6-10, 11-15, 16-20
        fsweep5<<<grd, blk, 0, stream>>>(u, bvec, Mv, invD, Mn, c, xa);
        sweep5w<false><<<grd, blk, 0, stream>>>(xa, c, Mn, xb);
        sweep5w<false><<<grd, blk, 0, stream>>>(xb, c, Mn, xa);
        sweep5w<true><<<grd, blk, 0, stream>>>(xa, c, Mn, out);
    } else {
        float* ping = (float*)d_ws;
        const float* src = u;
        for (int k = 0; k < maxiter; ++k) {
            float* dst = (((maxiter - 1 - k) & 1) == 0) ? out : ping;
            jac4_plain<<<dim3(nPts / 4 / 256), dim3(256), 0, stream>>>(src, bvec, Mv, invD, dst);
            src = dst;
        }
    }
}

// Round 8
// 127.735 us; speedup vs baseline: 1.4302x; 1.4302x over previous
//
#include <hip/hip_runtime.h>
#include <hip/hip_fp16.h>

// Batched 5-point-stencil Jacobi: x <- invD*(b - M x), 20 sweeps.
// B=16, N=512. Structure = fixed stencil (right,left,down,up), SEG=511*512.
// R7: revert to R5 geometry (64x32 tiles, 2048 blocks, 256 thr — proven), but
// fuse the coefficient fold into launch 1: coeffs computed per-block from raw
// fp32 inputs into registers, used for sweeps 1-5, tile coeffs written to ws
// for launches 2-4. Kills the fold's Mn/c/x0 round trip + its bank conflicts.

#define GN   512
#define GNN  (GN * GN)          // 2^18
#define GB   16
#define SEG  (GN * (GN - 1))    // 261632
#define SEG4 (4 * SEG)

// tile geometry (5 fused sweeps, tile 64 cols x 32 rows)
#define TW    64                // tile cols
#define TH    32                // tile rows
#define NGC   18                // col groups in region (cols rel -4..67)
#define NRR   40                // region rows (rel -4..35)
#define NGRP  (NGC * NRR)       // 720
#define XSTR  84                // x LDS row stride (halfs)
#define XROWS 42                // staged rows rel -5..36
#define XGC   20                // staged col groups (cols rel -8..71)

struct alignas(8)  h4  { __half h[4]; };
struct alignas(16) hx8 { __half h[8]; };

__device__ inline float h2f(__half v) { return __half2float(v); }

__device__ inline h4 f4h(float a, float b, float c, float d) {
    h4 r;
    *(__half2*)&r.h[0] = __floats2half2_rn(a, b);
    *(__half2*)&r.h[2] = __floats2half2_rn(c, d);
    return r;
}

// one 4-point group: o = c + m.(x neighbors), from LDS buffer s at base
__device__ inline void grp4(const __half* __restrict__ s, const int base,
                            const hx8& m01, const hx8& m23, const h4& cc,
                            float o[4])
{
    const h4 xc = *(const h4*)(s + base);
    const h4 xu = *(const h4*)(s + base - XSTR);
    const h4 xd = *(const h4*)(s + base + XSTR);
    const float xl = h2f(s[base - 1]);
    const float xr = h2f(s[base + 4]);
    const float x0 = h2f(xc.h[0]), x1 = h2f(xc.h[1]);
    const float x2 = h2f(xc.h[2]), x3 = h2f(xc.h[3]);

    float a;
    a = h2f(cc.h[0]);
    a = fmaf(h2f(m01.h[0]), x1, a);
    a = fmaf(h2f(m01.h[1]), xl, a);
    a = fmaf(h2f(m01.h[2]), h2f(xd.h[0]), a);
    a = fmaf(h2f(m01.h[3]), h2f(xu.h[0]), a);
    o[0] = a;
    a = h2f(cc.h[1]);
    a = fmaf(h2f(m01.h[4]), x2, a);
    a = fmaf(h2f(m01.h[5]), x0, a);
    a = fmaf(h2f(m01.h[6]), h2f(xd.h[1]), a);
    a = fmaf(h2f(m01.h[7]), h2f(xu.h[1]), a);
    o[1] = a;
    a = h2f(cc.h[2]);
    a = fmaf(h2f(m23.h[0]), x3, a);
    a = fmaf(h2f(m23.h[1]), x1, a);
    a = fmaf(h2f(m23.h[2]), h2f(xd.h[2]), a);
    a = fmaf(h2f(m23.h[3]), h2f(xu.h[2]), a);
    o[2] = a;
    a = h2f(cc.h[3]);
    a = fmaf(h2f(m23.h[4]), xr, a);
    a = fmaf(h2f(m23.h[5]), x2, a);
    a = fmaf(h2f(m23.h[6]), h2f(xd.h[3]), a);
    a = fmaf(h2f(m23.h[7]), h2f(xu.h[3]), a);
    o[3] = a;
}

// the 4 internal ping-pong phases (sweeps 1..4 of a 5-sweep launch)
__device__ inline void phases4(__half* __restrict__ xsA, __half* __restrict__ xsB,
                               const hx8 (&m01)[3], const hx8 (&m23)[3],
                               const h4 (&cc)[3], const int (&lb)[3],
                               const bool (&act)[3])
{
#pragma unroll
    for (int k = 0; k < 3; ++k) {
        if (!act[k]) continue;
        float o[4];
        grp4(xsA, lb[k], m01[k], m23[k], cc[k], o);
        *(h4*)(xsB + lb[k]) = f4h(o[0], o[1], o[2], o[3]);
    }
    __syncthreads();
#pragma unroll
    for (int k = 0; k < 3; ++k) {
        if (!act[k]) continue;
        float o[4];
        grp4(xsB, lb[k], m01[k], m23[k], cc[k], o);
        *(h4*)(xsA + lb[k]) = f4h(o[0], o[1], o[2], o[3]);
    }
    __syncthreads();
#pragma unroll
    for (int k = 0; k < 3; ++k) {
        if (!act[k]) continue;
        float o[4];
        grp4(xsA, lb[k], m01[k], m23[k], cc[k], o);
        *(h4*)(xsB + lb[k]) = f4h(o[0], o[1], o[2], o[3]);
    }
    __syncthreads();
#pragma unroll
    for (int k = 0; k < 3; ++k) {
        if (!act[k]) continue;
        float o[4];
        grp4(xsB, lb[k], m01[k], m23[k], cc[k], o);
        *(h4*)(xsA + lb[k]) = f4h(o[0], o[1], o[2], o[3]);
    }
    __syncthreads();
}

// ---- Launch 1: fold fused with sweeps 1-5, 64x32 tiles. Coeffs computed
// from raw fp32 inputs into registers; tile coeffs written to ws for L2-4.
// Out-of-image region groups get exact-zero coeffs (clean fringe).
__global__ __launch_bounds__(256) void fsweep5(
    const float* __restrict__ u,
    const float* __restrict__ bvec,
    const float* __restrict__ Mv,
    const float* __restrict__ invD,
    __half* __restrict__ MnW,    // [B][NN][4] out
    __half* __restrict__ cW,     // [B][NN] out
    __half* __restrict__ xout)   // [B][NN] out (after 5 sweeps)
{
    __shared__ __half xsA[XROWS * XSTR];
    __shared__ __half xsB[XROWS * XSTR];

    const int tid  = threadIdx.x;
    const int tile = blockIdx.x;          // 2048 blocks
    const int bi   = tile >> 7;
    const int tl   = tile & 127;
    const int j0   = (tl & 7) << 6;
    const int i0   = (tl >> 3) << 5;

    const float* __restrict__ ub  = u  + ((size_t)bi << 18);
    const float* __restrict__ mvb = Mv + (size_t)bi * SEG4;

    // stage x = fp16(u) region (rows rel -5..36, cols rel -8..71); 0 outside
    for (int v = tid; v < XROWS * XGC; v += 256) {
        const int r = v / XGC;
        const int g = v - r * XGC;
        const int gi = i0 + r - 5;
        const int gj = j0 - 8 + (g << 2);
        h4 val{};
        if ((unsigned)gi < GN && (unsigned)gj < GN) {
            const float4 f = *(const float4*)(ub + ((size_t)gi << 9) + gj);
            val = f4h(f.x, f.y, f.z, f.w);
        }
        *(h4*)(xsA + r * XSTR + (g << 2)) = val;
    }

    // per-thread coeffs/c for 3 fixed region groups, computed from raw inputs
    hx8 m01[3], m23[3]; h4 cc[3];
    int lb[3], rrA[3], gcA[3]; bool act[3];
#pragma unroll
    for (int k = 0; k < 3; ++k) {
        int gidx = tid + (k << 8);
        act[k] = gidx < NGRP;
        if (gidx >= NGRP) gidx = NGRP - 1;
        const int r   = gidx / NGC;              // 0..39
        const int g   = gidx - r * NGC;          // 0..17
        const int rr  = r - 4;                   // row rel -4..35
        const int gcc = (g << 2) - 4;            // col rel -4..64 (mult of 4)
        rrA[k] = rr; gcA[k] = gcc;
        lb[k] = (rr + 5) * XSTR + gcc + 8;
        const int gi = i0 + rr;
        const int gj = j0 + gcc;
        hx8 w01{}, w23{}; h4 ch{};
        if ((unsigned)gi < GN && (unsigned)gj < GN) {
            const size_t pg = ((size_t)bi << 18) + ((size_t)gi << 9) + gj;
            const float4 dd  = *(const float4*)(invD + pg);
            const float4 bb4 = *(const float4*)(bvec + pg);
            float4 md4 = make_float4(0.f, 0.f, 0.f, 0.f);
            float4 mu4 = make_float4(0.f, 0.f, 0.f, 0.f);
            if (gi < GN - 1) md4 = *(const float4*)(mvb + 2 * SEG + ((size_t)gi << 9) + gj);
            if (gi > 0)      mu4 = *(const float4*)(mvb + 3 * SEG + (((size_t)gi - 1) << 9) + gj);
            const float dv[4]  = {dd.x, dd.y, dd.z, dd.w};
            const float bv[4]  = {bb4.x, bb4.y, bb4.z, bb4.w};
            const float mdv[4] = {md4.x, md4.y, md4.z, md4.w};
            const float muv[4] = {mu4.x, mu4.y, mu4.z, mu4.w};
            const int e0 = gi * (GN - 1) + gj;
#pragma unroll
            for (int e = 0; e < 4; ++e) {
                const int j = gj + e;
                const float mr = (j < GN - 1) ? mvb[e0 + e]           : 0.0f;
                const float ml = (j > 0)      ? mvb[SEG + e0 + e - 1] : 0.0f;
                const __half2 a  = __floats2half2_rn(-dv[e] * mr, -dv[e] * ml);
                const __half2 b2 = __floats2half2_rn(-dv[e] * mdv[e], -dv[e] * muv[e]);
                if (e < 2) { *(__half2*)&w01.h[4*e]     = a; *(__half2*)&w01.h[4*e+2]     = b2; }
                else       { *(__half2*)&w23.h[4*(e-2)] = a; *(__half2*)&w23.h[4*(e-2)+2] = b2; }
                ch.h[e] = __float2half_rn(dv[e] * bv[e]);
            }
            // persist tile coeffs for launches 2-4 (each tile point once)
            if ((unsigned)rr < TH && (unsigned)gcc < TW) {
                *(hx8*)(MnW + (pg << 2))     = w01;
                *(hx8*)(MnW + (pg << 2) + 8) = w23;
                *(h4*)(cW + pg) = ch;
            }
        }
        m01[k] = w01; m23[k] = w23; cc[k] = ch;
    }
    __syncthreads();

    phases4(xsA, xsB, m01, m23, cc, lb, act);   // sweeps 1-4

    // sweep 5: A -> global (tile only), fp16
#pragma unroll
    for (int k = 0; k < 3; ++k) {
        if (!act[k]) continue;
        if ((unsigned)rrA[k] >= TH || (unsigned)gcA[k] >= TW) continue;
        float o[4];
        grp4(xsA, lb[k], m01[k], m23[k], cc[k], o);
        const size_t p = ((size_t)bi << 18) + (size_t)(i0 + rrA[k]) * GN + j0 + gcA[k];
        *(h4*)(xout + p) = f4h(o[0], o[1], o[2], o[3]);
    }
}

// ---- Launches 2-4: 5 fused sweeps from ws (fp16 Mn/c/x). Identical to R5's
// proven sweep5. Out-of-region coeff reads wrap within ws (finite garbage
// only; image-boundary edges have folded-zero coefficients).
template<bool FINAL>
__global__ __launch_bounds__(256) void sweep5w(
    const __half* __restrict__ x,
    const __half* __restrict__ cvec,
    const __half* __restrict__ Mn,
    void* __restrict__ xout)
{
    __shared__ __half xsA[XROWS * XSTR];
    __shared__ __half xsB[XROWS * XSTR];

    const int tid  = threadIdx.x;
    const int tile = blockIdx.x;          // 2048 tiles
    const int bi   = tile >> 7;
    const int tl   = tile & 127;
    const int j0   = (tl & 7) << 6;
    const int i0   = (tl >> 3) << 5;

    const __half* __restrict__ xb = x + ((size_t)bi << 18);

    // stage x region (rows rel -5..36, cols rel -8..71); 0 outside
    for (int v = tid; v < XROWS * XGC; v += 256) {
        const int r = v / XGC;
        const int g = v - r * XGC;
        const int gi = i0 + r - 5;
        const int gj = j0 - 8 + (g << 2);
        h4 val{};
        if ((unsigned)gi < GN && (unsigned)gj < GN)
            val = *(const h4*)(xb + ((size_t)gi << 9) + gj);
        *(h4*)(xsA + r * XSTR + (g << 2)) = val;
    }

    hx8 m01[3], m23[3]; h4 cc[3];
    int lb[3], rrA[3], gcA[3]; bool act[3];
#pragma unroll
    for (int k = 0; k < 3; ++k) {
        int gidx = tid + (k << 8);
        act[k] = gidx < NGRP;
        if (gidx >= NGRP) gidx = NGRP - 1;
        const int r   = gidx / NGC;
        const int g   = gidx - r * NGC;
        rrA[k] = r - 4;
        gcA[k] = (g << 2) - 4;
        lb[k] = (rrA[k] + 5) * XSTR + gcA[k] + 8;
        const long pg = ((long)bi << 18) + (long)(i0 + rrA[k]) * GN + (j0 + gcA[k]);
        const hx8* mp = (const hx8*)(Mn + (pg << 2));    // pg%4==0 -> 16B ok
        m01[k] = mp[0];
        m23[k] = mp[1];
        cc[k]  = *(const h4*)(cvec + pg);
    }
    __syncthreads();

    phases4(xsA, xsB, m01, m23, cc, lb, act);   // 4 sweeps

    // final sweep: A -> global (tile only)
#pragma unroll
    for (int k = 0; k < 3; ++k) {
        if (!act[k]) continue;
        if ((unsigned)rrA[k] >= TH || (unsigned)gcA[k] >= TW) continue;
        float o[4];
        grp4(xsA, lb[k], m01[k], m23[k], cc[k], o);
        const size_t p = ((size_t)bi << 18) + (size_t)(i0 + rrA[k]) * GN + j0 + gcA[k];
        if (FINAL)
            *(float4*)((float*)xout + p) = make_float4(o[0], o[1], o[2], o[3]);
        else
            *(h4*)((__half*)xout + p) = f4h(o[0], o[1], o[2], o[3]);
    }
}

// ---- fp32 fallback (ws too small): x' = invD*(b - M x), 4 pts/thread ----
__global__ __launch_bounds__(256) void jac4_plain(
    const float* __restrict__ x,
    const float* __restrict__ bvec,
    const float* __restrict__ Mv,
    const float* __restrict__ invD,
    float* __restrict__ xout)
{
    const int t  = blockIdx.x * 256 + threadIdx.x;
    const int q  = t << 2;
    const int bi = q >> 18;
    const int p  = q & (GNN - 1);
    const int i  = p >> 9;
    const int j  = p & (GN - 1);

    const float* __restrict__ xb = x  + ((size_t)bi << 18);
    const float* __restrict__ mb = Mv + (size_t)bi * SEG4;

    const float4 xc = *(const float4*)(xb + p);
    const float  xl = (j > 0)      ? xb[p - 1] : 0.0f;
    const float  xr = (j < GN - 4) ? xb[p + 4] : 0.0f;
    float4 xu = make_float4(0.f, 0.f, 0.f, 0.f);
    float4 xd = make_float4(0.f, 0.f, 0.f, 0.f);
    float4 m2 = make_float4(0.f, 0.f, 0.f, 0.f);
    float4 m3 = make_float4(0.f, 0.f, 0.f, 0.f);
    if (i < GN - 1) { xd = *(const float4*)(xb + p + GN); m2 = *(const float4*)(mb + 2 * SEG + p); }
    if (i > 0)      { xu = *(const float4*)(xb + p - GN); m3 = *(const float4*)(mb + 3 * SEG + p - GN); }
    const float* __restrict__ m0 = mb + i * (GN - 1) + j;
    const float* __restrict__ m1 = mb + SEG + i * (GN - 1) + j - 1;
    const float m00 = m0[0], m01 = m0[1], m02 = m0[2], m03 = m0[3];
    const float m10 = m1[0], m11 = m1[1], m12 = m1[2], m13 = m1[3];

    const float4 bb = *(const float4*)(bvec + (size_t)q);
    const float4 dd = *(const float4*)(invD + (size_t)q);

    float4 o;
    o.x = dd.x * (bb.x - (m00 * xc.y + m10 * xl   + m2.x * xd.x + m3.x * xu.x));
    o.y = dd.y * (bb.y - (m01 * xc.z + m11 * xc.x + m2.y * xd.y + m3.y * xu.y));
    o.z = dd.z * (bb.z - (m02 * xc.w + m12 * xc.y + m2.z * xd.z + m3.z * xu.z));
    o.w = dd.w * (bb.w - (m03 * xr   + m13 * xc.z + m2.w * xd.w + m3.w * xu.w));

    *(float4*)(xout + (size_t)q) = o;
}

extern "C" void kernel_launch(void* const* d_in, const int* in_sizes, int n_in,
                              void* d_out, int out_size, void* d_ws, size_t ws_size,
                              hipStream_t stream)
{
    const float* u    = (const float*)d_in[0];
    const float* bvec = (const float*)d_in[1];
    const float* Mv   = (const float*)d_in[2];
    const float* invD = (const float*)d_in[3];
    const int maxiter = 20;                      // fixed by setup_inputs

    float* out = (float*)d_out;
    const size_t nPts  = (size_t)GB * GNN;       // 4,194,304
    // layout: xa, xb, Mn, c, tail pad (wrapped coeff reads stay in-bounds)
    const size_t needB = (7 * nPts + 32768) * sizeof(__half);

    if (ws_size >= needB) {
        __half* xa = (__half*)d_ws;
        __half* xb = xa + nPts;
        __half* Mn = xb + nPts;
        __half* c  = Mn + 4 * nPts;

        const dim3 blk(256);
        const dim3 grd(2048);
        // sweeps 1-5 (+ fused fold), 6-10, 11-15, 16-20
        fsweep5<<<grd, blk, 0, stream>>>(u, bvec, Mv, invD, Mn, c, xa);
        sweep5w<false><<<grd, blk, 0, stream>>>(xa, c, Mn, xb);
        sweep5w<false><<<grd, blk, 0, stream>>>(xb, c, Mn, xa);
        sweep5w<true><<<grd, blk, 0, stream>>>(xa, c, Mn, out);
    } else {
        float* ping = (float*)d_ws;
        const float* src = u;
        for (int k = 0; k < maxiter; ++k) {
            float* dst = (((maxiter - 1 - k) & 1) == 0) ? out : ping;
            jac4_plain<<<dim3(nPts / 4 / 256), dim3(256), 0, stream>>>(src, bvec, Mv, invD, dst);
            src = dst;
        }
    }
}